// Round 1
// baseline (514.853 us; speedup 1.0000x reference)
//
#include <hip/hip_runtime.h>
#include <math.h>

// FlowAttention: B=4, L=S=4096, H=16, D=64, fp32.
// 5-pass linear-attention decomposition; softmax denom folded into epilogue.
#define B_ 4
#define L_ 4096
#define H_ 16
#define D_ 64
#define HD_ 1024   // row stride in elements between consecutive l for fixed (b,h) = H_*D_
#define EPSF 1e-6f

__device__ __forceinline__ float sigf(float x) { return 1.0f / (1.0f + __expf(-x)); }

// broadcast lane d's value to all lanes (SGPR operand for the FMA)
__device__ __forceinline__ float bcastf(float x, int l) {
    return __int_as_float(__builtin_amdgcn_readlane(__float_as_int(x), l));
}

__device__ __forceinline__ float redu1(float a) {
#pragma unroll
    for (int m = 1; m < 64; m <<= 1) a += __shfl_xor(a, m, 64);
    return a;
}

__device__ __forceinline__ void redu2(float& a, float& b) {
#pragma unroll
    for (int m = 1; m < 64; m <<= 1) {
        a += __shfl_xor(a, m, 64);
        b += __shfl_xor(b, m, 64);
    }
}

// P1: ksum[bh][d] = sum_s sigmoid(k[b,s,h,d])
__global__ __launch_bounds__(256) void k_ksum(const float* __restrict__ K,
                                              float* __restrict__ ksum) {
    int bh = blockIdx.x, b = bh >> 4, h = bh & 15;
    int t = threadIdx.x, lane = t & 63, w = t >> 6;
    int l0 = blockIdx.y * 512 + w * 128;
    const float* p = K + (size_t)b * L_ * HD_ + h * D_ + (size_t)l0 * HD_ + lane;
    float acc = 0.f;
    for (int i = 0; i < 128; i += 8) {
        float x[8];
#pragma unroll
        for (int j = 0; j < 8; j++) x[j] = p[(size_t)(i + j) * HD_];
#pragma unroll
        for (int j = 0; j < 8; j++) acc += sigf(x[j]);
    }
    __shared__ float sm[64];
    if (t < 64) sm[t] = 0.f;
    __syncthreads();
    atomicAdd(&sm[lane], acc);
    __syncthreads();
    if (t < 64) atomicAdd(&ksum[bh * 64 + t], sm[t]);
}

// P2: qsum[bh][d] = sum_l sigmoid(q);  qn[bh][d] = sum_l sigmoid(q)*nrow[l]
//     nrow[l] = 1/((sig(q[l])+EPS)·(ksum+EPS))  (recomputed again in P4)
__global__ __launch_bounds__(256) void k_qpass(const float* __restrict__ Q,
                                               const float* __restrict__ ksum,
                                               float* __restrict__ qsum,
                                               float* __restrict__ qn) {
    int bh = blockIdx.x, b = bh >> 4, h = bh & 15;
    int t = threadIdx.x, lane = t & 63, w = t >> 6;
    int l0 = blockIdx.y * 512 + w * 128;
    const float* p = Q + (size_t)b * L_ * HD_ + h * D_ + (size_t)l0 * HD_ + lane;
    float ksE = ksum[bh * 64 + lane] + EPSF;
    float qs = 0.f, qa = 0.f;
    float c0 = p[0], c1 = p[HD_], c2 = p[2 * HD_], c3 = p[3 * HD_];
    for (int i = 0; i < 128; i += 4) {
        float n0 = 0.f, n1 = 0.f, n2 = 0.f, n3 = 0.f;
        if (i + 4 < 128) {
            n0 = p[(size_t)(i + 4) * HD_];
            n1 = p[(size_t)(i + 5) * HD_];
            n2 = p[(size_t)(i + 6) * HD_];
            n3 = p[(size_t)(i + 7) * HD_];
        }
        float s0 = sigf(c0), s1 = sigf(c1), s2 = sigf(c2), s3 = sigf(c3);
        float d0 = redu1((s0 + EPSF) * ksE);
        float d1 = redu1((s1 + EPSF) * ksE);
        float d2 = redu1((s2 + EPSF) * ksE);
        float d3 = redu1((s3 + EPSF) * ksE);
        qs += s0 + s1 + s2 + s3;
        qa += s0 * __builtin_amdgcn_rcpf(d0) + s1 * __builtin_amdgcn_rcpf(d1) +
              s2 * __builtin_amdgcn_rcpf(d2) + s3 * __builtin_amdgcn_rcpf(d3);
        c0 = n0; c1 = n1; c2 = n2; c3 = n3;
    }
    __shared__ float smq[64], sma[64];
    if (t < 64) { smq[t] = 0.f; sma[t] = 0.f; }
    __syncthreads();
    atomicAdd(&smq[lane], qs);
    atomicAdd(&sma[lane], qa);
    __syncthreads();
    if (t < 64) {
        atomicAdd(&qsum[bh * 64 + t], smq[t]);
        atomicAdd(&qn[bh * 64 + t], sma[t]);
    }
}

// P3: per s-row: ncol = 1/((sk+E)·(qsum+E)); es = exp((sk+E)·(qn+E));
//     kn += sk*ncol; den += es; kv[d][e] += sk[d]*v[e]*es  (softmax denom folded later)
__global__ __launch_bounds__(256) void k_kv(const float* __restrict__ K,
                                            const float* __restrict__ V,
                                            const float* __restrict__ qsum,
                                            const float* __restrict__ qn,
                                            float* __restrict__ kn,
                                            float* __restrict__ den,
                                            float* __restrict__ kvp,
                                            int C, int rowsPerBlock) {
    int bh = blockIdx.x, b = bh >> 4, h = bh & 15;
    int c = blockIdx.y;
    int t = threadIdx.x, lane = t & 63, w = t >> 6;
    int nrows = rowsPerBlock >> 2;
    int l0 = c * rowsPerBlock + w * nrows;
    const float* kp = K + (size_t)b * L_ * HD_ + h * D_ + (size_t)l0 * HD_ + lane;
    const float* vp = V + (size_t)b * L_ * HD_ + h * D_ + (size_t)l0 * HD_ + lane;
    float qsE = qsum[bh * 64 + lane] + EPSF;
    float qnE = qn[bh * 64 + lane] + EPSF;
    __shared__ float smkv[4096];
    __shared__ float smkn[64];
    __shared__ float smden;
    for (int i = t; i < 4096; i += 256) smkv[i] = 0.f;
    if (t < 64) smkn[t] = 0.f;
    if (t == 0) smden = 0.f;
    __syncthreads();
    float acc[64];
#pragma unroll
    for (int d = 0; d < 64; d++) acc[d] = 0.f;
    float knacc = 0.f, dacc = 0.f;
    float kc = kp[0], vc = vp[0];
    for (int i = 0; i < nrows; i++) {
        float knx = 0.f, vnx = 0.f;
        if (i + 1 < nrows) {
            knx = kp[(size_t)(i + 1) * HD_];
            vnx = vp[(size_t)(i + 1) * HD_];
        }
        float sk = sigf(kc);
        float a = (sk + EPSF) * qsE;
        float e = (sk + EPSF) * qnE;
        redu2(a, e);                                   // a = ncol denom, e = softmax logit
        float ncol = __builtin_amdgcn_rcpf(a);
        float es = __expf(e);                          // logits ~O(1): no max-subtract needed
        knacc += sk * ncol;
        dacc += es;
        float vw = vc * es;
#pragma unroll
        for (int d = 0; d < 64; d++) acc[d] += bcastf(sk, d) * vw;  // lane e owns kv[:,e]
        kc = knx; vc = vnx;
    }
    atomicAdd(&smkn[lane], knacc);
    if (lane == 0) atomicAdd(&smden, dacc);
#pragma unroll
    for (int d = 0; d < 64; d++) atomicAdd(&smkv[d * 64 + lane], acc[d]);
    __syncthreads();
    if (t < 64) atomicAdd(&kn[bh * 64 + t], smkn[t]);
    if (t == 0) atomicAdd(&den[bh], smden);
    float* o = kvp + ((size_t)bh * C + c) * 4096;
    for (int i = t; i < 4096; i += 256) o[i] = smkv[i];
}

// P3b: reduce per-chunk kv partials
__global__ __launch_bounds__(256) void k_kvred(const float* __restrict__ kvp,
                                               float* __restrict__ kvf, int C) {
    int bh = blockIdx.x, t = threadIdx.x;
    for (int i = 0; i < 16; i++) {
        int idx = i * 256 + t;
        float s = 0.f;
        for (int c = 0; c < C; c++) s += kvp[((size_t)bh * C + c) * 4096 + idx];
        kvf[(size_t)bh * 4096 + idx] = s;
    }
}

// P4: x[l,e] = (sig(q[l])·kv[:,e]) * nrow[l] * rref[l] * S/den
__global__ __launch_bounds__(256) void k_out(const float* __restrict__ Q,
                                             const float* __restrict__ ksum,
                                             const float* __restrict__ kn,
                                             const float* __restrict__ den,
                                             const float* __restrict__ kvf,
                                             float* __restrict__ out) {
    int bh = blockIdx.x, b = bh >> 4, h = bh & 15;
    int t = threadIdx.x, lane = t & 63, w = t >> 6;
    int l0 = blockIdx.y * 256 + w * 64;
    const float* qp = Q + (size_t)b * L_ * HD_ + h * D_ + (size_t)l0 * HD_ + lane;
    float* op = out + (size_t)b * L_ * HD_ + h * D_ + (size_t)l0 * HD_ + lane;
    float ksE = ksum[bh * 64 + lane] + EPSF;
    float knE = kn[bh * 64 + lane] + EPSF;
    float sden = 4096.0f / den[bh];
    float kvr[64];
#pragma unroll
    for (int d = 0; d < 64; d++) kvr[d] = kvf[(size_t)bh * 4096 + d * 64 + lane];
    float q0 = qp[0], q1 = qp[HD_];
    for (int i = 0; i < 64; i += 2) {
        float p0 = 0.f, p1 = 0.f;
        if (i + 2 < 64) {
            p0 = qp[(size_t)(i + 2) * HD_];
            p1 = qp[(size_t)(i + 3) * HD_];
        }
        float s0 = sigf(q0), s1 = sigf(q1);
        float a0 = (s0 + EPSF) * ksE, b0 = (s0 + EPSF) * knE;
        float a1 = (s1 + EPSF) * ksE, b1 = (s1 + EPSF) * knE;
        redu2(a0, b0);
        redu2(a1, b1);
        float sc0 = __builtin_amdgcn_rcpf(a0) * sigf(b0) * sden;  // nrow * rref * S/den
        float sc1 = __builtin_amdgcn_rcpf(a1) * sigf(b1) * sden;
        float acc0 = 0.f, acc1 = 0.f;
#pragma unroll
        for (int d = 0; d < 64; d++) {
            acc0 += bcastf(s0, d) * kvr[d];
            acc1 += bcastf(s1, d) * kvr[d];
        }
        op[(size_t)i * HD_] = acc0 * sc0;
        op[(size_t)(i + 1) * HD_] = acc1 * sc1;
        q0 = p0; q1 = p1;
    }
}

extern "C" void kernel_launch(void* const* d_in, const int* in_sizes, int n_in,
                              void* d_out, int out_size, void* d_ws, size_t ws_size,
                              hipStream_t stream) {
    const float* Q = (const float*)d_in[0];
    const float* K = (const float*)d_in[1];
    const float* V = (const float*)d_in[2];
    float* out = (float*)d_out;
    float* ws = (float*)d_ws;
    // workspace layout (floats):
    float* ksum = ws;            // 4096
    float* qsum = ws + 4096;     // 4096
    float* qn   = ws + 8192;     // 4096
    float* kn   = ws + 12288;    // 4096
    float* den  = ws + 16384;    // 64
    float* kvf  = ws + 16448;    // 262144
    float* kvp  = ws + 278592;   // C*64*4096 partials

    int C3 = 8;
    while (C3 > 1 && (278592ull + (size_t)C3 * 262144ull) * 4ull > ws_size) C3 >>= 1;

    hipMemsetAsync(d_ws, 0, 16448ull * 4ull, stream);  // zero sums + den
    k_ksum<<<dim3(64, 8), 256, 0, stream>>>(K, ksum);
    k_qpass<<<dim3(64, 8), 256, 0, stream>>>(Q, ksum, qsum, qn);
    if (C3 > 1) {
        k_kv<<<dim3(64, C3), 256, 0, stream>>>(K, V, qsum, qn, kn, den, kvp, C3, L_ / C3);
        k_kvred<<<dim3(64), 256, 0, stream>>>(kvp, kvf, C3);
    } else {
        // ws too small for partials: single chunk per (b,h) writes kv directly
        k_kv<<<dim3(64, 1), 256, 0, stream>>>(K, V, qsum, qn, kn, den, kvf, 1, L_);
    }
    k_out<<<dim3(64, 16), 256, 0, stream>>>(Q, ksum, kn, den, kvf, out);
}

// Round 2
// 304.407 us; speedup vs baseline: 1.6913x; 1.6913x over previous
//
#include <hip/hip_runtime.h>
#include <math.h>
#include <stdint.h>

// FlowAttention B=4, L=S=4096, H=16, D=64 fp32.
// P1 ksum(K) -> P2 qsum,qn(Q) -> P3 kn,den,KV via MFMA (K,V) -> P4 out via MFMA (Q).
// GEMM-shaped contractions use bf16 hi/lo-split MFMA (3 mfma per tile-step, ~2^-16 rel err).
#define B_ 4
#define L_ 4096
#define H_ 16
#define EPSF 1e-6f
#define STR 66   // k_kv LDS row stride (words)
#define STRO 68  // k_out LDS row stride (words, 16B-aligned rows)

typedef short bf16x8 __attribute__((ext_vector_type(8)));
typedef float f32x4 __attribute__((ext_vector_type(4)));
union FragU { uint32_t u[4]; bf16x8 v; };

__device__ __forceinline__ float sigf(float x) { return 1.0f / (1.0f + __expf(-x)); }

// pack fp32 -> (bf16 hi | bf16 lo) in one 32-bit word. hi = truncate-to-bf16, lo = x - hi.
__device__ __forceinline__ uint32_t packhl(float x) {
    uint32_t xb = __float_as_uint(x);
    uint32_t hb = xb & 0xFFFF0000u;
    float lo = x - __uint_as_float(hb);
    return (hb >> 16) | (__float_as_uint(lo) & 0xFFFF0000u);
}

// 8 packed words (k-order) -> hi and lo bf16x8 fragments via v_perm
__device__ __forceinline__ void buildfrag(const uint32_t w[8], bf16x8& hi, bf16x8& lo) {
    FragU H, L;
#pragma unroll
    for (int t = 0; t < 4; ++t) {
        H.u[t] = __builtin_amdgcn_perm(w[2 * t + 1], w[2 * t], 0x05040100u);
        L.u[t] = __builtin_amdgcn_perm(w[2 * t + 1], w[2 * t], 0x07060302u);
    }
    hi = H.v; lo = L.v;
}

#define MFMA3(acc, ahi, alo, bhi, blo)                                        \
    acc = __builtin_amdgcn_mfma_f32_16x16x32_bf16(ahi, bhi, acc, 0, 0, 0);    \
    acc = __builtin_amdgcn_mfma_f32_16x16x32_bf16(ahi, blo, acc, 0, 0, 0);    \
    acc = __builtin_amdgcn_mfma_f32_16x16x32_bf16(alo, bhi, acc, 0, 0, 0);

// ---------------- P1: ksum[d] = sum_s sigmoid(K) ----------------
__global__ __launch_bounds__(256) void k_ksum(const float* __restrict__ K,
                                              float* __restrict__ ksum) {
    int bh = blockIdx.x, b = bh >> 4, h = bh & 15;
    int t = threadIdx.x, lane = t & 63, w = t >> 6;
    int q4 = lane >> 4, i16 = lane & 15;
    int r0 = blockIdx.y * 256 + w * 64;
    float a0 = 0.f, a1 = 0.f, a2 = 0.f, a3 = 0.f;
    for (int it = 0; it < 16; ++it) {
        int r = r0 + it * 4 + q4;
        float4 x = *(const float4*)(K + (((size_t)b * L_ + r) * H_ + h) * 64 + 4 * i16);
        a0 += sigf(x.x); a1 += sigf(x.y); a2 += sigf(x.z); a3 += sigf(x.w);
    }
#pragma unroll
    for (int m = 16; m < 64; m <<= 1) {
        a0 += __shfl_xor(a0, m, 64); a1 += __shfl_xor(a1, m, 64);
        a2 += __shfl_xor(a2, m, 64); a3 += __shfl_xor(a3, m, 64);
    }
    if (q4 == 0) {
        atomicAdd(&ksum[bh * 64 + 4 * i16 + 0], a0);
        atomicAdd(&ksum[bh * 64 + 4 * i16 + 1], a1);
        atomicAdd(&ksum[bh * 64 + 4 * i16 + 2], a2);
        atomicAdd(&ksum[bh * 64 + 4 * i16 + 3], a3);
    }
}

// ---------------- P2: qsum[d], qn[d] ----------------
__global__ __launch_bounds__(256) void k_qpass(const float* __restrict__ Q,
                                               const float* __restrict__ ksum,
                                               float* __restrict__ qsum,
                                               float* __restrict__ qn) {
    int bh = blockIdx.x, b = bh >> 4, h = bh & 15;
    int t = threadIdx.x, lane = t & 63, w = t >> 6;
    int q4 = lane >> 4, i16 = lane & 15;
    int r0 = blockIdx.y * 256 + w * 64;
    float4 ks4 = *(const float4*)(ksum + bh * 64 + 4 * i16);
    ks4.x += EPSF; ks4.y += EPSF; ks4.z += EPSF; ks4.w += EPSF;
    float qs0 = 0.f, qs1 = 0.f, qs2 = 0.f, qs3 = 0.f;
    float qa0 = 0.f, qa1 = 0.f, qa2 = 0.f, qa3 = 0.f;
    for (int it = 0; it < 16; ++it) {
        int r = r0 + it * 4 + q4;
        float4 x = *(const float4*)(Q + (((size_t)b * L_ + r) * H_ + h) * 64 + 4 * i16);
        float s0 = sigf(x.x), s1 = sigf(x.y), s2 = sigf(x.z), s3 = sigf(x.w);
        float pa = (s0 + EPSF) * ks4.x + (s1 + EPSF) * ks4.y +
                   (s2 + EPSF) * ks4.z + (s3 + EPSF) * ks4.w;
#pragma unroll
        for (int m = 1; m < 16; m <<= 1) pa += __shfl_xor(pa, m, 64);
        float nr = __builtin_amdgcn_rcpf(pa);
        qs0 += s0; qs1 += s1; qs2 += s2; qs3 += s3;
        qa0 += s0 * nr; qa1 += s1 * nr; qa2 += s2 * nr; qa3 += s3 * nr;
    }
#pragma unroll
    for (int m = 16; m < 64; m <<= 1) {
        qs0 += __shfl_xor(qs0, m, 64); qs1 += __shfl_xor(qs1, m, 64);
        qs2 += __shfl_xor(qs2, m, 64); qs3 += __shfl_xor(qs3, m, 64);
        qa0 += __shfl_xor(qa0, m, 64); qa1 += __shfl_xor(qa1, m, 64);
        qa2 += __shfl_xor(qa2, m, 64); qa3 += __shfl_xor(qa3, m, 64);
    }
    if (q4 == 0) {
        atomicAdd(&qsum[bh * 64 + 4 * i16 + 0], qs0);
        atomicAdd(&qsum[bh * 64 + 4 * i16 + 1], qs1);
        atomicAdd(&qsum[bh * 64 + 4 * i16 + 2], qs2);
        atomicAdd(&qsum[bh * 64 + 4 * i16 + 3], qs3);
        atomicAdd(&qn[bh * 64 + 4 * i16 + 0], qa0);
        atomicAdd(&qn[bh * 64 + 4 * i16 + 1], qa1);
        atomicAdd(&qn[bh * 64 + 4 * i16 + 2], qa2);
        atomicAdd(&qn[bh * 64 + 4 * i16 + 3], qa3);
    }
}

// ---------------- P3: kn, den, KV += SK^T (V*es) via MFMA ----------------
__global__ __launch_bounds__(256) void k_kv(const float* __restrict__ K,
                                            const float* __restrict__ V,
                                            const float* __restrict__ qsum,
                                            const float* __restrict__ qn,
                                            float* __restrict__ kn,
                                            float* __restrict__ den,
                                            float* __restrict__ KVg) {
    int bh = blockIdx.x, b = bh >> 4, h = bh & 15;
    int t = threadIdx.x, lane = t & 63, w = t >> 6;
    int q4 = lane >> 4, i16 = lane & 15;
    __shared__ uint32_t skp[64 * STR];
    __shared__ uint32_t vwp[64 * STR];
    float4 qsE = *(const float4*)(qsum + bh * 64 + 4 * i16);
    float4 qnE = *(const float4*)(qn + bh * 64 + 4 * i16);
    qsE.x += EPSF; qsE.y += EPSF; qsE.z += EPSF; qsE.w += EPSF;
    qnE.x += EPSF; qnE.y += EPSF; qnE.z += EPSF; qnE.w += EPSF;
    f32x4 acc[4];
#pragma unroll
    for (int tm = 0; tm < 4; ++tm) acc[tm] = (f32x4){0.f, 0.f, 0.f, 0.f};
    float kn0 = 0.f, kn1 = 0.f, kn2 = 0.f, kn3 = 0.f, dacc = 0.f;
    int rowbase = blockIdx.y * 256;
    for (int tile = 0; tile < 4; ++tile) {
        // ---- cooperative staging: wave w stages rows [w*16, w*16+16) of this 64-row tile
#pragma unroll
        for (int j = 0; j < 4; ++j) {
            int lr = w * 16 + j * 4 + q4;
            int r = rowbase + tile * 64 + lr;
            size_t off = (((size_t)b * L_ + r) * H_ + h) * 64 + 4 * i16;
            float4 kx = *(const float4*)(K + off);
            float s0 = sigf(kx.x), s1 = sigf(kx.y), s2 = sigf(kx.z), s3 = sigf(kx.w);
            float pa = (s0 + EPSF) * qsE.x + (s1 + EPSF) * qsE.y +
                       (s2 + EPSF) * qsE.z + (s3 + EPSF) * qsE.w;
            float pc = (s0 + EPSF) * qnE.x + (s1 + EPSF) * qnE.y +
                       (s2 + EPSF) * qnE.z + (s3 + EPSF) * qnE.w;
#pragma unroll
            for (int m = 1; m < 16; m <<= 1) {
                pa += __shfl_xor(pa, m, 64);
                pc += __shfl_xor(pc, m, 64);
            }
            float ncol = __builtin_amdgcn_rcpf(pa);
            float es = __expf(pc);                 // logits O(1): no max-subtract needed
            kn0 += s0 * ncol; kn1 += s1 * ncol; kn2 += s2 * ncol; kn3 += s3 * ncol;
            if (i16 == 0) dacc += es;
            uint32_t* sp = &skp[lr * STR + 4 * i16];
            *(uint2*)sp = make_uint2(packhl(s0), packhl(s1));
            *(uint2*)(sp + 2) = make_uint2(packhl(s2), packhl(s3));
            float4 vx = *(const float4*)(V + off);
            uint32_t* vp = &vwp[lr * STR + 4 * i16];
            *(uint2*)vp = make_uint2(packhl(vx.x * es), packhl(vx.y * es));
            *(uint2*)(vp + 2) = make_uint2(packhl(vx.z * es), packhl(vx.w * es));
        }
        __syncthreads();
        // ---- MFMA: wave w owns e-tile tn=w; KV[d][e] += sum_row SK[row][d]*VW[row][e]
#pragma unroll
        for (int ks = 0; ks < 2; ++ks) {
            uint32_t bw[8];
#pragma unroll
            for (int j = 0; j < 8; ++j)
                bw[j] = vwp[(32 * ks + 8 * q4 + j) * STR + 16 * w + i16];
            bf16x8 bhi, blo; buildfrag(bw, bhi, blo);
#pragma unroll
            for (int tm = 0; tm < 4; ++tm) {
                uint32_t aw[8];
#pragma unroll
                for (int j = 0; j < 8; ++j)
                    aw[j] = skp[(32 * ks + 8 * q4 + j) * STR + 16 * tm + i16];
                bf16x8 ahi, alo; buildfrag(aw, ahi, alo);
                MFMA3(acc[tm], ahi, alo, bhi, blo);
            }
        }
        __syncthreads();
    }
    // ---- KV partial: D[m=d][n=e], row=(lane>>4)*4+reg, col=lane&15 (m89-verified)
#pragma unroll
    for (int tm = 0; tm < 4; ++tm)
#pragma unroll
        for (int r = 0; r < 4; ++r)
            atomicAdd(&KVg[(size_t)bh * 4096 + (16 * tm + 4 * q4 + r) * 64 + 16 * w + i16],
                      acc[tm][r]);
#pragma unroll
    for (int m = 16; m < 64; m <<= 1) {
        kn0 += __shfl_xor(kn0, m, 64); kn1 += __shfl_xor(kn1, m, 64);
        kn2 += __shfl_xor(kn2, m, 64); kn3 += __shfl_xor(kn3, m, 64);
    }
    if (q4 == 0) {
        atomicAdd(&kn[bh * 64 + 4 * i16 + 0], kn0);
        atomicAdd(&kn[bh * 64 + 4 * i16 + 1], kn1);
        atomicAdd(&kn[bh * 64 + 4 * i16 + 2], kn2);
        atomicAdd(&kn[bh * 64 + 4 * i16 + 3], kn3);
    }
#pragma unroll
    for (int m = 1; m < 64; m <<= 1) dacc += __shfl_xor(dacc, m, 64);
    if (lane == 0) atomicAdd(&den[bh], dacc);
}

// ---------------- P4: out = (SQ·KV) * nrow * rref * S/den via MFMA ----------------
__global__ __launch_bounds__(256) void k_out(const float* __restrict__ Q,
                                             const float* __restrict__ ksum,
                                             const float* __restrict__ kn,
                                             const float* __restrict__ den,
                                             const float* __restrict__ KVg,
                                             float* __restrict__ out) {
    int bh = blockIdx.x, b = bh >> 4, h = bh & 15;
    int t = threadIdx.x, lane = t & 63, w = t >> 6;
    int q4 = lane >> 4, i16 = lane & 15;
    __shared__ uint32_t kvt[64 * STRO];        // packed KV^T: [e][d]
    __shared__ uint32_t sqp[4][16 * STRO];     // per-wave 16-row SQ staging
    __shared__ float scale_s[4][16];
    float4 ksE = *(const float4*)(ksum + bh * 64 + 4 * i16);
    float4 knE = *(const float4*)(kn + bh * 64 + 4 * i16);
    ksE.x += EPSF; ksE.y += EPSF; ksE.z += EPSF; ksE.w += EPSF;
    knE.x += EPSF; knE.y += EPSF; knE.z += EPSF; knE.w += EPSF;
    float sden = 4096.0f * __builtin_amdgcn_rcpf(den[bh]);
    for (int idx = t; idx < 4096; idx += 256) {
        float x = KVg[(size_t)bh * 4096 + idx];
        kvt[(idx & 63) * STRO + (idx >> 6)] = packhl(x);
    }
    __syncthreads();
    int rowbase = blockIdx.y * 256;
    for (int g = 0; g < 4; ++g) {
        int r0 = rowbase + w * 64 + g * 16;
        // ---- stage this wave's 16 rows (wave-private: no barrier needed)
#pragma unroll
        for (int j = 0; j < 4; ++j) {
            int lr = j * 4 + q4;
            int r = r0 + lr;
            float4 qx = *(const float4*)(Q + (((size_t)b * L_ + r) * H_ + h) * 64 + 4 * i16);
            float s0 = sigf(qx.x), s1 = sigf(qx.y), s2 = sigf(qx.z), s3 = sigf(qx.w);
            float pa = (s0 + EPSF) * ksE.x + (s1 + EPSF) * ksE.y +
                       (s2 + EPSF) * ksE.z + (s3 + EPSF) * ksE.w;
            float pb = (s0 + EPSF) * knE.x + (s1 + EPSF) * knE.y +
                       (s2 + EPSF) * knE.z + (s3 + EPSF) * knE.w;
#pragma unroll
            for (int m = 1; m < 16; m <<= 1) {
                pa += __shfl_xor(pa, m, 64);
                pb += __shfl_xor(pb, m, 64);
            }
            float sc = __builtin_amdgcn_rcpf(pa) * sigf(pb) * sden;  // nrow*rref*S/den
            if (i16 == 0) scale_s[w][lr] = sc;
            uint32_t* sp = &sqp[w][lr * STRO + 4 * i16];
            *(uint4*)sp = make_uint4(packhl(s0), packhl(s1), packhl(s2), packhl(s3));
        }
        f32x4 acc[4];
#pragma unroll
        for (int tn = 0; tn < 4; ++tn) acc[tn] = (f32x4){0.f, 0.f, 0.f, 0.f};
#pragma unroll
        for (int ks = 0; ks < 2; ++ks) {
            const uint32_t* ap = &sqp[w][i16 * STRO + 32 * ks + 8 * q4];
            uint4 a0 = *(const uint4*)ap, a1 = *(const uint4*)(ap + 4);
            uint32_t aw[8] = {a0.x, a0.y, a0.z, a0.w, a1.x, a1.y, a1.z, a1.w};
            bf16x8 ahi, alo; buildfrag(aw, ahi, alo);
#pragma unroll
            for (int tn = 0; tn < 4; ++tn) {
                const uint32_t* bp = &kvt[(16 * tn + i16) * STRO + 32 * ks + 8 * q4];
                uint4 b0 = *(const uint4*)bp, b1 = *(const uint4*)(bp + 4);
                uint32_t bw[8] = {b0.x, b0.y, b0.z, b0.w, b1.x, b1.y, b1.z, b1.w};
                bf16x8 bhi, blo; buildfrag(bw, bhi, blo);
                MFMA3(acc[tn], ahi, alo, bhi, blo);
            }
        }
#pragma unroll
        for (int tn = 0; tn < 4; ++tn)
#pragma unroll
            for (int r = 0; r < 4; ++r) {
                int rl = 4 * q4 + r;
                float sc = scale_s[w][rl];
                out[(((size_t)b * L_ + (r0 + rl)) * H_ + h) * 64 + 16 * tn + i16] =
                    acc[tn][r] * sc;
            }
    }
}

extern "C" void kernel_launch(void* const* d_in, const int* in_sizes, int n_in,
                              void* d_out, int out_size, void* d_ws, size_t ws_size,
                              hipStream_t stream) {
    const float* Q = (const float*)d_in[0];
    const float* K = (const float*)d_in[1];
    const float* V = (const float*)d_in[2];
    float* out = (float*)d_out;
    float* ws = (float*)d_ws;
    float* ksum = ws;          // 4096
    float* qsum = ws + 4096;   // 4096
    float* qn   = ws + 8192;   // 4096
    float* kn   = ws + 12288;  // 4096
    float* den  = ws + 16384;  // 64
    float* KVg  = ws + 16448;  // 64*64*64 = 262144

    hipMemsetAsync(d_ws, 0, (16448ull + 262144ull) * 4ull, stream);
    k_ksum<<<dim3(64, 16), 256, 0, stream>>>(K, ksum);
    k_qpass<<<dim3(64, 16), 256, 0, stream>>>(Q, ksum, qsum, qn);
    k_kv<<<dim3(64, 16), 256, 0, stream>>>(K, V, qsum, qn, kn, den, KVg);
    k_out<<<dim3(64, 16), 256, 0, stream>>>(Q, ksum, kn, den, KVg, out);
}